// Round 10
// baseline (485.008 us; speedup 1.0000x reference)
//
#include <hip/hip_runtime.h>
#include <math.h>

typedef __attribute__((ext_vector_type(8))) short short8;
typedef __attribute__((ext_vector_type(4))) float f32x4;
typedef unsigned short u16;
typedef unsigned int u32;

__device__ inline u16 f2b(float f) {  // f32 -> bf16 round-to-nearest-even
  u32 u = __float_as_uint(f);
  return (u16)((u + 0x7FFFu + ((u >> 16) & 1u)) >> 16);
}
__device__ inline float b2f(u16 b) { return __uint_as_float((u32)b << 16); }
__device__ inline float lrelu(float v) { return v > 0.f ? v : 0.2f * v; }
__device__ inline float elu1(float v) { return v > 0.f ? v : __expf(v) - 1.f; }

__device__ inline void gld_lds16(const void* g, void* l) {
  __builtin_amdgcn_global_load_lds((const __attribute__((address_space(1))) void*)g,
                                   (__attribute__((address_space(3))) void*)l, 16, 0, 0);
}

// ---------------- fused prep: weight casts + deg_count + wsd projection ----------
// Coalesced-write transposes (r9): strided reads hit L2/L3 (W1/2/3 cache-resident).
__global__ void fused_prep(const float* __restrict__ W1, u16* __restrict__ Wt1,
                           const float* __restrict__ W2, u16* __restrict__ Wt2,
                           const float* __restrict__ W3, u16* __restrict__ Wt3,
                           const int* __restrict__ ei, int E0, int ET,
                           int* __restrict__ deg, const float* __restrict__ as1,
                           const float* __restrict__ ad1, float* __restrict__ wsd) {
  int i = blockIdx.x * blockDim.x + threadIdx.x;
  if (i < 64 * 512) {          // Wt1[n*64+k] = W1[k*512+n]
    int n = i >> 6, k = i & 63;
    Wt1[n * 64 + k] = f2b(W1[k * 512 + n]);
    return;
  }
  i -= 64 * 512;
  if (i < 512 * 512) {         // Wt2[n*512+k] = W2[k*512+n]
    int n = i >> 9, k = i & 511;
    Wt2[n * 512 + k] = f2b(W2[k * 512 + n]);
    return;
  }
  i -= 512 * 512;
  if (i < 512 * 128) {         // Wt3[n*512+k] = W3[k*128+n]
    int n = i >> 9, k = i & 511;
    Wt3[n * 512 + k] = f2b(W3[k * 128 + n]);
    return;
  }
  i -= 512 * 128;
  if (i < ET) {
    int d = (i < E0) ? ei[E0 + i] : (i - E0);
    atomicAdd(&deg[d], 1);
    return;
  }
  i -= ET;
  if (i < 512) {  // wsd[k][0..3]=W1_h@a_src, [4..7]=W1_h@a_dst (layer-1 proj)
    int k = i >> 3, c8 = i & 7, hh = c8 & 3;
    const float* a = (c8 >= 4) ? ad1 : as1;
    float s = 0.f;
    for (int c = 0; c < 128; ++c) s += W1[k * 512 + hh * 128 + c] * a[hh * 128 + c];
    wsd[k * 8 + c8] = s;
  }
}

// ---------------- bf16 MFMA GEMM (layer 2): LDS XOR-swizzle + 2-phase dbuf -------
__global__ __launch_bounds__(256) void gemm_bf16_gat(
    const u16* __restrict__ A, const u16* __restrict__ Bt, u16* __restrict__ Hb,
    const float* __restrict__ a_src, const float* __restrict__ a_dst,
    float* __restrict__ aS, float* __restrict__ aD, int M, int HC, int K, int Hh,
    int gy, int nStrips) {
  int mIdx, nIdx;
  if (nStrips == 4) {
    int l = blockIdx.x;
    int xcd = l & 7, k = l >> 3;
    nIdx = k & 3;
    mIdx = xcd + 8 * (k >> 2);
    if (mIdx >= gy) return;
  } else {
    mIdx = blockIdx.x;
    nIdx = 0;
  }
  __shared__ u16 As[2][128 * 32];
  __shared__ u16 Bs[2][128 * 32];
  __shared__ float sRed[2][2][128];
  const int tid = threadIdx.x;
  const int w = tid >> 6, lane = tid & 63;
  const int wm = w >> 1, wn = w & 1;
  const int q = lane >> 4, l15 = lane & 15;
  const int nBase = nIdx * 128;
  const int mBase = mIdx * 128;
  const int h = nBase >> 7;
  const int srow = lane >> 2;
  const int ssw = ((lane & 3) ^ ((lane >> 3) & 3)) * 8;
  const int rq = (q ^ ((l15 >> 1) & 3)) * 8;

  f32x4 acc[4][4];
#pragma unroll
  for (int i = 0; i < 4; ++i)
#pragma unroll
    for (int j = 0; j < 4; ++j) acc[i][j] = (f32x4){0.f, 0.f, 0.f, 0.f};

  const int nSteps = K >> 5;
#pragma unroll
  for (int r = 0; r < 2; ++r) {
    int lrow0 = w * 32 + r * 16;
    int ga = mBase + lrow0 + srow;
    if (ga >= M) ga = M - 1;
    gld_lds16(A + (size_t)ga * K + ssw, &As[0][lrow0 * 32]);
    int gb = nBase + lrow0 + srow;
    gld_lds16(Bt + (size_t)gb * K + ssw, &Bs[0][lrow0 * 32]);
  }
  __syncthreads();
  int cur = 0;
  for (int step = 0; step < nSteps; ++step) {
    const int k0n = (step + 1) << 5;
    if (k0n < K) {
#pragma unroll
      for (int r = 0; r < 2; ++r) {
        int lrow0 = w * 32 + r * 16;
        int ga = mBase + lrow0 + srow;
        if (ga >= M) ga = M - 1;
        gld_lds16(A + (size_t)ga * K + k0n + ssw, &As[cur ^ 1][lrow0 * 32]);
        int gb = nBase + lrow0 + srow;
        gld_lds16(Bt + (size_t)gb * K + k0n + ssw, &Bs[cur ^ 1][lrow0 * 32]);
      }
    }
    short8 af[4], bf[4];
#pragma unroll
    for (int i = 0; i < 4; ++i)
      af[i] = *(const short8*)&As[cur][(wm * 64 + i * 16 + l15) * 32 + rq];
#pragma unroll
    for (int j = 0; j < 4; ++j)
      bf[j] = *(const short8*)&Bs[cur][(wn * 64 + j * 16 + l15) * 32 + rq];
#pragma unroll
    for (int i = 0; i < 4; ++i)
#pragma unroll
      for (int j = 0; j < 4; ++j)
        acc[i][j] = __builtin_amdgcn_mfma_f32_16x16x32_bf16(af[i], bf[j], acc[i][j], 0, 0, 0);
    __syncthreads();
    cur ^= 1;
  }

  float asv[4], adv[4];
#pragma unroll
  for (int j = 0; j < 4; ++j) {
    int cw = wn * 64 + j * 16 + l15;
    asv[j] = a_src[h * 128 + cw];
    adv[j] = a_dst[h * 128 + cw];
  }
#pragma unroll
  for (int mi = 0; mi < 4; ++mi) {
#pragma unroll
    for (int r = 0; r < 4; ++r) {
      int row = mBase + wm * 64 + mi * 16 + q * 4 + r;
      float s = 0.f, d = 0.f;
#pragma unroll
      for (int j = 0; j < 4; ++j) {
        float v = acc[mi][j][r];
        s = fmaf(v, asv[j], s);
        d = fmaf(v, adv[j], d);
        if (row < M) Hb[(size_t)row * HC + nBase + wn * 64 + j * 16 + l15] = f2b(v);
      }
#pragma unroll
      for (int o = 8; o; o >>= 1) {
        s += __shfl_xor(s, o);
        d += __shfl_xor(d, o);
      }
      if (l15 == 0) {
        int lr = wm * 64 + mi * 16 + q * 4 + r;
        sRed[0][wn][lr] = s;
        sRed[1][wn][lr] = d;
      }
    }
  }
  __syncthreads();
  if (tid < 128) {
    int row = mBase + tid;
    if (row < M) {
      aS[(size_t)row * Hh + h] = sRed[0][0][tid] + sRed[0][1][tid];
      aD[(size_t)row * Hh + h] = sRed[1][0][tid] + sRed[1][1][tid];
    }
  }
}

// ---------------- layer-3 GEMM: 64-row tiles (782 blocks), fused aS/aD epilogue --
__global__ __launch_bounds__(256) void gemm_bf16_l3(
    const u16* __restrict__ A, const u16* __restrict__ Bt,
    const float* __restrict__ a_src, const float* __restrict__ a_dst,
    u16* __restrict__ Hb, float* __restrict__ aS, float* __restrict__ aD, int M) {
  __shared__ u16 As[2][64 * 32];
  __shared__ u16 Bs[2][128 * 32];
  const int tid = threadIdx.x;
  const int w = tid >> 6, lane = tid & 63;
  const int q = lane >> 4, l15 = lane & 15;
  const int mBase = blockIdx.x * 64;
  const int ssw = ((lane & 3) ^ ((lane >> 3) & 3)) * 8;
  const int rq = (q ^ ((l15 >> 1) & 3)) * 8;
  const int arow = w * 16 + (lane >> 2);

  f32x4 acc[8];
#pragma unroll
  for (int j = 0; j < 8; ++j) acc[j] = (f32x4){0.f, 0.f, 0.f, 0.f};

  {
    int ga = mBase + arow;
    if (ga >= M) ga = M - 1;
    gld_lds16(A + (size_t)ga * 512 + ssw, &As[0][w * 512]);
#pragma unroll
    for (int r = 0; r < 2; ++r) {
      int brow = r * 64 + w * 16 + (lane >> 2);
      gld_lds16(Bt + (size_t)brow * 512 + ssw, &Bs[0][(r * 64 + w * 16) * 32]);
    }
  }
  __syncthreads();
  int cur = 0;
  for (int step = 0; step < 16; ++step) {
    if (step < 15) {
      const int k0n = (step + 1) << 5;
      int ga = mBase + arow;
      if (ga >= M) ga = M - 1;
      gld_lds16(A + (size_t)ga * 512 + k0n + ssw, &As[cur ^ 1][w * 512]);
#pragma unroll
      for (int r = 0; r < 2; ++r) {
        int brow = r * 64 + w * 16 + (lane >> 2);
        gld_lds16(Bt + (size_t)brow * 512 + k0n + ssw,
                  &Bs[cur ^ 1][(r * 64 + w * 16) * 32]);
      }
    }
    short8 af = *(const short8*)&As[cur][(w * 16 + l15) * 32 + rq];
    short8 bf[8];
#pragma unroll
    for (int j = 0; j < 8; ++j)
      bf[j] = *(const short8*)&Bs[cur][(j * 16 + l15) * 32 + rq];
#pragma unroll
    for (int j = 0; j < 8; ++j)
      acc[j] = __builtin_amdgcn_mfma_f32_16x16x32_bf16(af, bf[j], acc[j], 0, 0, 0);
    __syncthreads();
    cur ^= 1;
  }

  float asv[8], adv[8];
#pragma unroll
  for (int j = 0; j < 8; ++j) {
    asv[j] = a_src[j * 16 + l15];
    adv[j] = a_dst[j * 16 + l15];
  }
#pragma unroll
  for (int r = 0; r < 4; ++r) {
    int row = mBase + w * 16 + q * 4 + r;
    float s = 0.f, d = 0.f;
#pragma unroll
    for (int j = 0; j < 8; ++j) {
      float v = acc[j][r];
      s = fmaf(v, asv[j], s);
      d = fmaf(v, adv[j], d);
      if (row < M) Hb[(size_t)row * 128 + j * 16 + l15] = f2b(v);
    }
#pragma unroll
    for (int o = 8; o; o >>= 1) {
      s += __shfl_xor(s, o);
      d += __shfl_xor(d, o);
    }
    if (l15 == 0 && row < M) {
      aS[row] = s;
      aD[row] = d;
    }
  }
}

// ---------------- layer-1 block-diagonal GEMM (swizzle + dbuf, K=64) ------------
__global__ __launch_bounds__(256) void gemm_bd_l1(
    const u16* __restrict__ A, const u16* __restrict__ Bt,
    const float* __restrict__ bias, u16* __restrict__ outB, int M, int gy) {
  int l = blockIdx.x;
  int xcd = l & 7, kk = l >> 3;
  int nIdx = kk & 3;
  int mIdx = xcd + 8 * (kk >> 2);
  if (mIdx >= gy) return;
  __shared__ u16 As[2][128 * 32];
  __shared__ u16 Bs[2][128 * 32];
  const int tid = threadIdx.x;
  const int w = tid >> 6, lane = tid & 63;
  const int wm = w >> 1, wn = w & 1;
  const int q = lane >> 4, l15 = lane & 15;
  const int nBase = nIdx * 128, mBase = mIdx * 128;
  const int srow = lane >> 2;
  const int ssw = ((lane & 3) ^ ((lane >> 3) & 3)) * 8;
  const int rq = (q ^ ((l15 >> 1) & 3)) * 8;

  f32x4 acc[4][4];
#pragma unroll
  for (int i = 0; i < 4; ++i)
#pragma unroll
    for (int j = 0; j < 4; ++j) acc[i][j] = (f32x4){0.f, 0.f, 0.f, 0.f};

#pragma unroll
  for (int r = 0; r < 2; ++r) {
    int lrow0 = w * 32 + r * 16;
    int ga = mBase + lrow0 + srow;
    if (ga >= M) ga = M - 1;
    gld_lds16(A + (size_t)ga * 256 + nIdx * 64 + ssw, &As[0][lrow0 * 32]);
    int gb = nBase + lrow0 + srow;
    gld_lds16(Bt + (size_t)gb * 64 + ssw, &Bs[0][lrow0 * 32]);
  }
  __syncthreads();
  int cur = 0;
#pragma unroll
  for (int step = 0; step < 2; ++step) {
    if (step == 0) {
#pragma unroll
      for (int r = 0; r < 2; ++r) {
        int lrow0 = w * 32 + r * 16;
        int ga = mBase + lrow0 + srow;
        if (ga >= M) ga = M - 1;
        gld_lds16(A + (size_t)ga * 256 + nIdx * 64 + 32 + ssw, &As[1][lrow0 * 32]);
        int gb = nBase + lrow0 + srow;
        gld_lds16(Bt + (size_t)gb * 64 + 32 + ssw, &Bs[1][lrow0 * 32]);
      }
    }
    short8 af[4], bf[4];
#pragma unroll
    for (int i = 0; i < 4; ++i)
      af[i] = *(const short8*)&As[cur][(wm * 64 + i * 16 + l15) * 32 + rq];
#pragma unroll
    for (int j = 0; j < 4; ++j)
      bf[j] = *(const short8*)&Bs[cur][(wn * 64 + j * 16 + l15) * 32 + rq];
#pragma unroll
    for (int i = 0; i < 4; ++i)
#pragma unroll
      for (int j = 0; j < 4; ++j)
        acc[i][j] = __builtin_amdgcn_mfma_f32_16x16x32_bf16(af[i], bf[j], acc[i][j], 0, 0, 0);
    __syncthreads();
    cur ^= 1;
  }

  float bvv[4];
#pragma unroll
  for (int j = 0; j < 4; ++j) bvv[j] = bias[nBase + wn * 64 + j * 16 + l15];
#pragma unroll
  for (int mi = 0; mi < 4; ++mi)
#pragma unroll
    for (int r = 0; r < 4; ++r) {
      int row = mBase + wm * 64 + mi * 16 + q * 4 + r;
      if (row < M) {
#pragma unroll
        for (int j = 0; j < 4; ++j) {
          float v = elu1(acc[mi][j][r] + bvv[j]);
          outB[(size_t)row * 512 + nBase + wn * 64 + j * 16 + l15] = f2b(v);
        }
      }
    }
}

// ---------------- CSR scan ----------------
__global__ __launch_bounds__(256) void scan_chunk(const int* __restrict__ deg,
                                                  int* __restrict__ incl,
                                                  int* __restrict__ bsums, int N) {
  __shared__ int sdata[256];
  const int t = threadIdx.x;
  const int base = blockIdx.x * 2048;
  int v[8];
  int sum = 0;
#pragma unroll
  for (int i = 0; i < 8; ++i) {
    int idx = base + t * 8 + i;
    v[i] = (idx < N) ? deg[idx] : 0;
    sum += v[i];
  }
  sdata[t] = sum;
  __syncthreads();
  for (int off = 1; off < 256; off <<= 1) {
    int x = (t >= off) ? sdata[t - off] : 0;
    __syncthreads();
    sdata[t] += x;
    __syncthreads();
  }
  int run = (t > 0) ? sdata[t - 1] : 0;
#pragma unroll
  for (int i = 0; i < 8; ++i) {
    int idx = base + t * 8 + i;
    run += v[i];
    if (idx < N) incl[idx] = run;
  }
  if (t == 255) bsums[blockIdx.x] = sdata[255];
}

__global__ void scan_final(const int* __restrict__ incl, const int* __restrict__ bsums,
                           int* __restrict__ rowptr, int N, int nb) {
  int i = blockIdx.x * blockDim.x + threadIdx.x;
  if (i >= N) return;
  int chunk = i >> 11;
  int pre = 0;
  for (int j = 0; j < chunk; ++j) pre += bsums[j];
  rowptr[i + 1] = incl[i] + pre;
  if (i == 0) rowptr[0] = 0;
}

// csr_fill: writes layer-1 elog inline (asad_x runs before this).
__global__ void csr_fill(const int* __restrict__ ei, int E0, int ET,
                         const int* __restrict__ rowptr, int* __restrict__ cnt,
                         int* __restrict__ csr_src, int* __restrict__ csr_dst,
                         const float* __restrict__ aS, const float* __restrict__ aD,
                         float* __restrict__ elog) {
  int e = blockIdx.x * blockDim.x + threadIdx.x;
  if (e >= ET) return;
  int s, d;
  if (e < E0) { s = ei[e]; d = ei[E0 + e]; }
  else        { s = e - E0; d = e - E0; }
  int pos = atomicAdd(&cnt[d], 1);
  int slot = rowptr[d] + pos;
  csr_src[slot] = s;
  csr_dst[slot] = d;
  float4 a = *(const float4*)&aS[(size_t)s * 4];
  float4 b = *(const float4*)&aD[(size_t)d * 4];
  float4 r;
  r.x = lrelu(a.x + b.x);
  r.y = lrelu(a.y + b.y);
  r.z = lrelu(a.z + b.z);
  r.w = lrelu(a.w + b.w);
  *(float4*)&elog[(size_t)slot * 4] = r;
}

// aS[v,h] = x[v]·ws_h, aD[v,h] = x[v]·wd_h — one wave per node, f32 path.
__global__ __launch_bounds__(256) void asad_x(const float* __restrict__ xf,
                                              const float* __restrict__ wsd,
                                              float* __restrict__ aS,
                                              float* __restrict__ aD, int N) {
  const int wid = (int)((blockIdx.x * (blockDim.x >> 6)) + (threadIdx.x >> 6));
  const int lane = threadIdx.x & 63;
  if (wid >= N) return;
  float xv = xf[(size_t)wid * 64 + lane];
  float4 w0 = *(const float4*)&wsd[lane * 8];
  float4 w1 = *(const float4*)&wsd[lane * 8 + 4];
  float s[8] = {xv * w0.x, xv * w0.y, xv * w0.z, xv * w0.w,
                xv * w1.x, xv * w1.y, xv * w1.z, xv * w1.w};
#pragma unroll
  for (int i = 0; i < 8; ++i)
#pragma unroll
    for (int o = 32; o; o >>= 1) s[i] += __shfl_xor(s[i], o);
  if (lane == 0) {
    *(float4*)&aS[(size_t)wid * 4] = make_float4(s[0], s[1], s[2], s[3]);
    *(float4*)&aD[(size_t)wid * 4] = make_float4(s[4], s[5], s[6], s[7]);
  }
}

// ---------------- edge-parallel logit precompute (layer 2) ----------------
__global__ __launch_bounds__(256) void edge_logits(const int* __restrict__ csr_src,
                                                   const int* __restrict__ csr_dst,
                                                   const float* __restrict__ aS,
                                                   const float* __restrict__ aD,
                                                   float* __restrict__ elog, int ET,
                                                   int Hh) {
  int e = blockIdx.x * blockDim.x + threadIdx.x;
  if (e >= ET) return;
  int s = csr_src[e], d = csr_dst[e];
  if (Hh == 4) {
    float4 a = *(const float4*)&aS[(size_t)s * 4];
    float4 b = *(const float4*)&aD[(size_t)d * 4];
    float4 r;
    r.x = lrelu(a.x + b.x);
    r.y = lrelu(a.y + b.y);
    r.z = lrelu(a.z + b.z);
    r.w = lrelu(a.w + b.w);
    *(float4*)&elog[(size_t)e * 4] = r;
  } else {
    elog[e] = lrelu(aS[s] + aD[d]);
  }
}

// ---------------- layer-1 input-side aggregation ----------------
__global__ __launch_bounds__(256) void gat_agg_x(
    const int* __restrict__ rowptr, const int* __restrict__ csr_src,
    const float* __restrict__ xf, const float* __restrict__ elog,
    u16* __restrict__ aggB, int N) {
  const int wid = (int)((blockIdx.x * (blockDim.x >> 6)) + (threadIdx.x >> 6));
  const int lane = threadIdx.x & 63;
  if (wid >= N) return;
  const int beg = rowptr[wid];
  const int deg = rowptr[wid + 1] - beg;
  const int h = lane >> 4;
  const int e16 = lane & 15;
  float acc[4] = {};

  if (deg <= 16) {
    int srcv = 0;
    float l = -1e30f;
    if (e16 < deg) {
      srcv = csr_src[beg + e16];
      l = elog[(size_t)(beg + e16) * 4 + h];
    }
    float xv[16];
#pragma unroll
    for (int j = 0; j < 16; ++j)
      if (j < deg) {
        int s = __shfl(srcv, j);
        xv[j] = xf[(size_t)s * 64 + lane];
      }
    float m = l;
#pragma unroll
    for (int o = 8; o; o >>= 1) m = fmaxf(m, __shfl_xor(m, o));
    float pexp = (e16 < deg) ? __expf(l - m) : 0.f;
    float cs = pexp;
#pragma unroll
    for (int o = 8; o; o >>= 1) cs += __shfl_xor(cs, o);
    pexp *= (1.f / cs);
#pragma unroll
    for (int j = 0; j < 16; ++j)
      if (j < deg) {
        float w0 = __shfl(pexp, j);
        float w1 = __shfl(pexp, 16 | j);
        float w2 = __shfl(pexp, 32 | j);
        float w3 = __shfl(pexp, 48 | j);
        acc[0] = fmaf(w0, xv[j], acc[0]);
        acc[1] = fmaf(w1, xv[j], acc[1]);
        acc[2] = fmaf(w2, xv[j], acc[2]);
        acc[3] = fmaf(w3, xv[j], acc[3]);
      }
  } else {
    float m = -1e30f, ssum = 0.f;
    for (int c = 0; c < deg; c += 16) {
      const int ce = min(16, deg - c);
      int srcv = 0;
      float l = -1e30f;
      if (e16 < ce) {
        srcv = csr_src[beg + c + e16];
        l = elog[(size_t)(beg + c + e16) * 4 + h];
      }
      float xv[16];
#pragma unroll
      for (int j = 0; j < 16; ++j)
        if (j < ce) {
          int s = __shfl(srcv, j);
          xv[j] = xf[(size_t)s * 64 + lane];
        }
      float cm = l;
#pragma unroll
      for (int o = 8; o; o >>= 1) cm = fmaxf(cm, __shfl_xor(cm, o));
      float pexp, cs;
      if (c == 0) {
        m = cm;
        pexp = (e16 < ce) ? __expf(l - m) : 0.f;
        cs = pexp;
#pragma unroll
        for (int o = 8; o; o >>= 1) cs += __shfl_xor(cs, o);
        ssum = cs;
      } else {
        float newm = fmaxf(m, cm);
        float r = __expf(m - newm);
        m = newm;
        pexp = (e16 < ce) ? __expf(l - m) : 0.f;
        cs = pexp;
#pragma unroll
        for (int o = 8; o; o >>= 1) cs += __shfl_xor(cs, o);
        ssum = ssum * r + cs;
#pragma unroll
        for (int i = 0; i < 4; ++i) acc[i] *= r;
      }
#pragma unroll
      for (int j = 0; j < 16; ++j)
        if (j < ce) {
          float w0 = __shfl(pexp, j);
          float w1 = __shfl(pexp, 16 | j);
          float w2 = __shfl(pexp, 32 | j);
          float w3 = __shfl(pexp, 48 | j);
          acc[0] = fmaf(w0, xv[j], acc[0]);
          acc[1] = fmaf(w1, xv[j], acc[1]);
          acc[2] = fmaf(w2, xv[j], acc[2]);
          acc[3] = fmaf(w3, xv[j], acc[3]);
        }
    }
    const float inv = 1.f / ssum;
#pragma unroll
    for (int i = 0; i < 4; ++i) acc[i] *= inv;
  }
#pragma unroll
  for (int hh = 0; hh < 4; ++hh)
    aggB[((size_t)wid * 4 + hh) * 64 + lane] = f2b(acc[hh]);
}

// bf16 pair unpack: lo = u<<16, hi = u & 0xffff0000 — 1 VALU op per element.
#define ACC8(A, pv, wgt)                                             \
  A[0] = fmaf(wgt, __uint_as_float(pv.x << 16), A[0]);               \
  A[1] = fmaf(wgt, __uint_as_float(pv.x & 0xffff0000u), A[1]);       \
  A[2] = fmaf(wgt, __uint_as_float(pv.y << 16), A[2]);               \
  A[3] = fmaf(wgt, __uint_as_float(pv.y & 0xffff0000u), A[3]);       \
  A[4] = fmaf(wgt, __uint_as_float(pv.z << 16), A[4]);               \
  A[5] = fmaf(wgt, __uint_as_float(pv.z & 0xffff0000u), A[5]);       \
  A[6] = fmaf(wgt, __uint_as_float(pv.w << 16), A[6]);               \
  A[7] = fmaf(wgt, __uint_as_float(pv.w & 0xffff0000u), A[7]);

// ---------------- fused softmax + aggregate, Hh=4 (layer 2): r6 structure -------
// At its algorithmic gather floor (~460MB demand @ ~6.5TB/s delivered).
__global__ __launch_bounds__(256) void gat_fused_agg(
    const int* __restrict__ rowptr, const int* __restrict__ csr_src,
    const u16* __restrict__ Hb, const float* __restrict__ elog,
    const float* __restrict__ bias, u16* __restrict__ outB, int N) {
  const int wid = (int)((blockIdx.x * (blockDim.x >> 6)) + (threadIdx.x >> 6));
  const int lane = threadIdx.x & 63;
  if (wid >= N) return;
  const int beg = rowptr[wid];
  const int deg = rowptr[wid + 1] - beg;

  const int h = lane >> 4;
  const int e16 = lane & 15;
  const int c0 = lane * 8;
  const int hbase = lane & 48;
  float acc[8] = {};

  if (deg <= 16) {
    int srcv = 0;
    float l = -1e30f;
    if (e16 < deg) {
      srcv = csr_src[beg + e16];
      l = elog[(size_t)(beg + e16) * 4 + h];
    }
    uint4 pC[4];
#pragma unroll
    for (int j = 0; j < 4; ++j)
      if (j < deg) {
        int s = __shfl(srcv, j);
        pC[j] = *(const uint4*)&Hb[(size_t)s * 512 + c0];
      }
    float m = l;
#pragma unroll
    for (int o = 8; o; o >>= 1) m = fmaxf(m, __shfl_xor(m, o));
    float pexp = (e16 < deg) ? __expf(l - m) : 0.f;
    float cs = pexp;
#pragma unroll
    for (int o = 8; o; o >>= 1) cs += __shfl_xor(cs, o);
    pexp *= (1.f / cs);
    int e = 0;
    for (; e + 4 < deg; e += 4) {
      uint4 pN[4];
      int rem = deg - e - 4;
#pragma unroll
      for (int j = 0; j < 4; ++j)
        if (j < rem) {
          int s = __shfl(srcv, e + 4 + j);
          pN[j] = *(const uint4*)&Hb[(size_t)s * 512 + c0];
        }
#pragma unroll
      for (int j = 0; j < 4; ++j) {
        float wgt = __shfl(pexp, hbase | (e + j));
        ACC8(acc, pC[j], wgt)
      }
#pragma unroll
      for (int j = 0; j < 4; ++j) pC[j] = pN[j];
    }
#pragma unroll
    for (int j = 0; j < 4; ++j)
      if (j < deg - e) {
        float wgt = __shfl(pexp, hbase | (e + j));
        ACC8(acc, pC[j], wgt)
      }
  } else {
    float m = -1e30f, ssum = 0.f;
    for (int c = 0; c < deg; c += 16) {
      const int ce = min(16, deg - c);
      int srcv = 0;
      float l = -1e30f;
      if (e16 < ce) {
        srcv = csr_src[beg + c + e16];
        l = elog[(size_t)(beg + c + e16) * 4 + h];
      }
      float cm = l;
#pragma unroll
      for (int o = 8; o; o >>= 1) cm = fmaxf(cm, __shfl_xor(cm, o));
      float pexp, cs;
      if (c == 0) {
        m = cm;
        pexp = __expf(l - m);
        cs = pexp;
#pragma unroll
        for (int o = 8; o; o >>= 1) cs += __shfl_xor(cs, o);
        ssum = cs;
      } else {
        float newm = fmaxf(m, cm);
        float r = __expf(m - newm);
        m = newm;
        pexp = __expf(l - m);
        cs = pexp;
#pragma unroll
        for (int o = 8; o; o >>= 1) cs += __shfl_xor(cs, o);
        ssum = ssum * r + cs;
#pragma unroll
        for (int i = 0; i < 8; ++i) acc[i] *= r;
      }
      int e = 0;
      for (; e + 4 <= ce; e += 4) {
        int se0 = __shfl(srcv, e + 0), se1 = __shfl(srcv, e + 1);
        int se2 = __shfl(srcv, e + 2), se3 = __shfl(srcv, e + 3);
        float w0 = __shfl(pexp, hbase | (e + 0)), w1 = __shfl(pexp, hbase | (e + 1));
        float w2 = __shfl(pexp, hbase | (e + 2)), w3 = __shfl(pexp, hbase | (e + 3));
        uint4 p0 = *(const uint4*)&Hb[(size_t)se0 * 512 + c0];
        uint4 p1 = *(const uint4*)&Hb[(size_t)se1 * 512 + c0];
        uint4 p2 = *(const uint4*)&Hb[(size_t)se2 * 512 + c0];
        uint4 p3 = *(const uint4*)&Hb[(size_t)se3 * 512 + c0];
        ACC8(acc, p0, w0)
        ACC8(acc, p1, w1)
        ACC8(acc, p2, w2)
        ACC8(acc, p3, w3)
      }
      for (; e < ce; ++e) {
        int se = __shfl(srcv, e);
        float wgt = __shfl(pexp, hbase | e);
        uint4 pv = *(const uint4*)&Hb[(size_t)se * 512 + c0];
        ACC8(acc, pv, wgt)
      }
    }
    const float inv = 1.f / ssum;
#pragma unroll
    for (int i = 0; i < 8; ++i) acc[i] *= inv;
  }

  float bv[8];
  *(float4*)&bv[0] = *(const float4*)&bias[c0];
  *(float4*)&bv[4] = *(const float4*)&bias[c0 + 4];
  u16 packed[8];
#pragma unroll
  for (int i = 0; i < 8; ++i) {
    float v = elu1(acc[i] + bv[i]);
    packed[i] = f2b(v);
  }
  *(uint4*)&outB[(size_t)wid * 512 + c0] = *(const uint4*)packed;
}

// ---------------- Hh=1 aggregate (layer 3) + FUSED FC HEAD ----------------
// r10: (a) logits computed inline (aS gather overlaps the Hb gathers already in
// flight — deletes the layer-3 edge_logits pass); (b) fc_head fused into the
// epilogue: per node 128 shfl-broadcast + 128 FMA + 64-lane reduce slots into the
// gather-stall VALU idle (~55%); deletes the 51MB bufF round trip + a dispatch.
__global__ __launch_bounds__(256) void gat_agg_h1(
    const int* __restrict__ rowptr, const int* __restrict__ csr_src,
    const u16* __restrict__ Hb, const float* __restrict__ aSb,
    const float* __restrict__ aDb, const float* __restrict__ bias,
    const float* __restrict__ fc1w, const float* __restrict__ fc1b,
    const float* __restrict__ fc2w, const float* __restrict__ fc2b,
    float* __restrict__ out, int N) {
  const int wid = (int)((blockIdx.x * (blockDim.x >> 6)) + (threadIdx.x >> 6));
  const int lane = threadIdx.x & 63;
  if (wid >= N) return;
  const int beg = rowptr[wid];
  const int deg = rowptr[wid + 1] - beg;
  const int g = lane & 15;
  const int es = lane >> 4;
  const int c0 = g * 8;
  const float adh = aDb[wid];
  float acc[8] = {};

  if (deg <= 64) {
    int srcv = 0;
    if (lane < deg) srcv = csr_src[beg + lane];
    float av = aSb[srcv];  // masked lanes: srcv=0, in-bounds, unused
    const int dm1 = deg - 1;
    uint4 pC;
    {
      int s = __shfl(srcv, min(es, dm1));
      pC = *(const uint4*)&Hb[(size_t)s * 128 + c0];
    }
    float l = (lane < deg) ? lrelu(av + adh) : -1e30f;
    float m = l;
#pragma unroll
    for (int o = 32; o; o >>= 1) m = fmaxf(m, __shfl_xor(m, o));
    float pexp = (lane < deg) ? __expf(l - m) : 0.f;
    float cs = pexp;
#pragma unroll
    for (int o = 32; o; o >>= 1) cs += __shfl_xor(cs, o);
    pexp *= (1.f / cs);
    int t = 0;
    for (; t + 4 < deg; t += 4) {
      uint4 pN;
      {
        int s = __shfl(srcv, min(t + 4 + es, dm1));
        pN = *(const uint4*)&Hb[(size_t)s * 128 + c0];
      }
      float w = __shfl(pexp, t + es);
      ACC8(acc, pC, w)
      pC = pN;
    }
    {
      int idx = t + es;
      float w = __shfl(pexp, min(idx, dm1));
      if (idx > dm1) w = 0.f;
      ACC8(acc, pC, w)
    }
  } else {
    float m = -1e30f, ssum = 0.f;
    for (int c = 0; c < deg; c += 64) {
      const int ce = min(64, deg - c);
      int srcv = 0;
      float l = -1e30f;
      if (lane < ce) {
        srcv = csr_src[beg + c + lane];
        l = lrelu(aSb[srcv] + adh);
      }
      float cm = l;
#pragma unroll
      for (int o = 32; o; o >>= 1) cm = fmaxf(cm, __shfl_xor(cm, o));
      float pexp, cs;
      if (c == 0) {
        m = cm;
        pexp = __expf(l - m);
        cs = pexp;
#pragma unroll
        for (int o = 32; o; o >>= 1) cs += __shfl_xor(cs, o);
        ssum = cs;
      } else {
        float newm = fmaxf(m, cm);
        float r = __expf(m - newm);
        m = newm;
        pexp = __expf(l - m);
        cs = pexp;
#pragma unroll
        for (int o = 32; o; o >>= 1) cs += __shfl_xor(cs, o);
        ssum = ssum * r + cs;
#pragma unroll
        for (int i = 0; i < 8; ++i) acc[i] *= r;
      }
      for (int t = 0; t < ce; t += 4) {
        int idx = t + es;
        int se = __shfl(srcv, idx & 63);
        float wgt = __shfl(pexp, idx & 63);
        if (idx < ce) {
          uint4 pv = *(const uint4*)&Hb[(size_t)se * 128 + c0];
          ACC8(acc, pv, wgt)
        }
      }
    }
    const float inv = 1.f / ssum;
#pragma unroll
    for (int i = 0; i < 8; ++i) acc[i] *= inv;
  }
#pragma unroll
  for (int i = 0; i < 8; ++i) {
    acc[i] += __shfl_xor(acc[i], 16);
    acc[i] += __shfl_xor(acc[i], 32);
  }
  // ---- node output in registers: col k lives in lane (k>>3), slot (k&7) ----
  float o[8];
#pragma unroll
  for (int i = 0; i < 8; ++i) o[i] = elu1(acc[i] + bias[c0 + i]);
  // lanes >= 16 hold duplicate/garbage; only lanes 0-15 are shuffled from.
  // ---- FC1 (128 -> 64): lane j computes p_j; 4 partial sums break the FMA chain
  float p0 = 0.f, p1 = 0.f, p2 = 0.f, p3 = 0.f;
#pragma unroll
  for (int k = 0; k < 128; k += 4) {
    float v0 = __shfl(o[(k + 0) & 7], (k + 0) >> 3);
    float v1 = __shfl(o[(k + 1) & 7], (k + 1) >> 3);
    float v2 = __shfl(o[(k + 2) & 7], (k + 2) >> 3);
    float v3 = __shfl(o[(k + 3) & 7], (k + 3) >> 3);
    p0 = fmaf(v0, fc1w[(k + 0) * 64 + lane], p0);
    p1 = fmaf(v1, fc1w[(k + 1) * 64 + lane], p1);
    p2 = fmaf(v2, fc1w[(k + 2) * 64 + lane], p2);
    p3 = fmaf(v3, fc1w[(k + 3) * 64 + lane], p3);
  }
  float p = (p0 + p1) + (p2 + p3);
  p = fmaxf(p + fc1b[lane], 0.f);
  // ---- FC2 (64 -> 1) + sigmoid ----
  float s = p * fc2w[lane];
#pragma unroll
  for (int off = 32; off; off >>= 1) s += __shfl_xor(s, off);
  if (lane == 0) out[wid] = 1.f / (1.f + __expf(-(s + fc2b[0])));
}

// ---------------- launch ----------------
extern "C" void kernel_launch(void* const* d_in, const int* in_sizes, int n_in,
                              void* d_out, int out_size, void* d_ws, size_t ws_size,
                              hipStream_t stream) {
  const float* x    = (const float*)d_in[0];
  const int*   ei   = (const int*)d_in[1];
  const float* W1   = (const float*)d_in[2];
  const float* as1  = (const float*)d_in[3];
  const float* ad1  = (const float*)d_in[4];
  const float* b1   = (const float*)d_in[5];
  const float* W2   = (const float*)d_in[6];
  const float* as2  = (const float*)d_in[7];
  const float* ad2  = (const float*)d_in[8];
  const float* b2   = (const float*)d_in[9];
  const float* W3   = (const float*)d_in[10];
  const float* as3  = (const float*)d_in[11];
  const float* ad3  = (const float*)d_in[12];
  const float* b3   = (const float*)d_in[13];
  const float* fc1w = (const float*)d_in[14];
  const float* fc1b = (const float*)d_in[15];
  const float* fc2w = (const float*)d_in[16];
  const float* fc2b = (const float*)d_in[17];
  float* out = (float*)d_out;

  const int N  = in_sizes[0] / 64;  // 50000
  const int E0 = in_sizes[1] / 2;   // 400000
  const int ET = E0 + N;

  char* ws = (char*)d_ws;
  size_t off = 0;
  auto alloc = [&](size_t bytes) -> void* {
    void* p = ws + off;
    off += (bytes + 255) & ~(size_t)255;
    return p;
  };
  u16*   bufXb   = (u16*)alloc((size_t)N * 512 * 2);
  u16*   bufHb   = (u16*)alloc((size_t)N * 512 * 2);
  float* aS      = (float*)alloc((size_t)N * 4 * 4);
  float* aD      = (float*)alloc((size_t)N * 4 * 4);
  u16*   Wt1     = (u16*)alloc((size_t)512 * 64 * 2);
  u16*   Wt2     = (u16*)alloc((size_t)512 * 512 * 2);
  u16*   Wt3     = (u16*)alloc((size_t)128 * 512 * 2);
  u16*   aggB    = (u16*)alloc((size_t)N * 256 * 2);
  float* wsd     = (float*)alloc((size_t)64 * 8 * 4);
  int*   degcnt  = (int*)alloc((size_t)2 * N * 4);
  int*   deg     = degcnt;
  int*   cnt     = degcnt + N;
  int*   incl    = (int*)alloc((size_t)N * 4);
  int*   rowptr  = (int*)alloc((size_t)(N + 1) * 4);
  int*   bsums   = (int*)alloc(256 * 4);
  int*   csr_src = (int*)alloc((size_t)ET * 4);
  int*   csr_dst = (int*)alloc((size_t)ET * 4);
  float* elog    = (float*)alloc((size_t)ET * 4 * 4);  // [e][h], Hh<=4
  (void)ws_size; (void)n_in; (void)out_size;

  // ---- prep: zero deg/cnt, weight casts + degree count + wsd ----
  hipMemsetAsync(degcnt, 0, (size_t)2 * N * 4, stream);
  const int prepTotal = 64 * 512 + 512 * 512 + 512 * 128 + ET + 512;
  hipLaunchKernelGGL(fused_prep, dim3((prepTotal + 255) / 256), dim3(256), 0, stream,
                     W1, Wt1, W2, Wt2, W3, Wt3, ei, E0, ET, deg, as1, ad1, wsd);

  // ---- CSR scan ----
  int nb = (N + 2047) / 2048;
  hipLaunchKernelGGL(scan_chunk, dim3(nb), dim3(256), 0, stream, deg, incl, bsums, N);
  hipLaunchKernelGGL(scan_final, dim3((N + 255) / 256), dim3(256), 0, stream, incl, bsums,
                     rowptr, N, nb);

  const int gy = (N + 127) / 128;                 // 391 m-tiles
  const int grid4 = ((gy + 7) / 8) * 8 * 4;       // XCD-swizzled 1-D grid, 4 strips
  const int aggGrid = (N + 3) / 4;                // 4 waves x 1 node per block
  int eb = (ET + 255) / 256;

  // ---- layer 1: aS/aD first (x-based), then csr_fill writes elog1 inline ----
  hipLaunchKernelGGL(asad_x, dim3(aggGrid), dim3(256), 0, stream, x, wsd, aS, aD, N);
  hipLaunchKernelGGL(csr_fill, dim3(eb), dim3(256), 0, stream, ei, E0, ET, rowptr, cnt,
                     csr_src, csr_dst, aS, aD, elog);
  hipLaunchKernelGGL(gat_agg_x, dim3(aggGrid), dim3(256), 0, stream, rowptr, csr_src, x,
                     elog, aggB, N);
  hipLaunchKernelGGL(gemm_bd_l1, dim3(grid4), dim3(256), 0, stream, aggB, Wt1, b1,
                     bufXb, N, gy);

  // ---- layer 2: [N,512] -> [N,512] ----
  hipLaunchKernelGGL(gemm_bf16_gat, dim3(grid4), dim3(256), 0, stream, bufXb, Wt2, bufHb,
                     as2, ad2, aS, aD, N, 512, 512, 4, gy, 4);
  hipLaunchKernelGGL(edge_logits, dim3(eb), dim3(256), 0, stream, csr_src, csr_dst, aS,
                     aD, elog, ET, 4);
  hipLaunchKernelGGL(gat_fused_agg, dim3(aggGrid), dim3(256), 0, stream, rowptr,
                     csr_src, bufHb, elog, b2, bufXb, N);

  // ---- layer 3: [N,512] -> [N,128] GEMM, then agg + inline logits + fused FC ----
  hipLaunchKernelGGL(gemm_bf16_l3, dim3((N + 63) / 64), dim3(256), 0, stream, bufXb,
                     Wt3, as3, ad3, bufHb, aS, aD, N);
  hipLaunchKernelGGL(gat_agg_h1, dim3(aggGrid), dim3(256), 0, stream, rowptr, csr_src,
                     bufHb, aS, aD, b3, fc1w, fc1b, fc2w, fc2b, out, N);
}

// Round 11
// 439.495 us; speedup vs baseline: 1.1036x; 1.1036x over previous
//
#include <hip/hip_runtime.h>
#include <math.h>

typedef __attribute__((ext_vector_type(8))) short short8;
typedef __attribute__((ext_vector_type(4))) float f32x4;
typedef unsigned short u16;
typedef unsigned int u32;

__device__ inline u16 f2b(float f) {  // f32 -> bf16 round-to-nearest-even
  u32 u = __float_as_uint(f);
  return (u16)((u + 0x7FFFu + ((u >> 16) & 1u)) >> 16);
}
__device__ inline float b2f(u16 b) { return __uint_as_float((u32)b << 16); }
__device__ inline float lrelu(float v) { return v > 0.f ? v : 0.2f * v; }
__device__ inline float elu1(float v) { return v > 0.f ? v : __expf(v) - 1.f; }

__device__ inline void gld_lds16(const void* g, void* l) {
  __builtin_amdgcn_global_load_lds((const __attribute__((address_space(1))) void*)g,
                                   (__attribute__((address_space(3))) void*)l, 16, 0, 0);
}

// ---------------- fused prep: weight casts + deg_count + wsd projection ----------
// Coalesced-write transposes (r9): strided reads hit L2/L3 (W1/2/3 cache-resident).
__global__ void fused_prep(const float* __restrict__ W1, u16* __restrict__ Wt1,
                           const float* __restrict__ W2, u16* __restrict__ Wt2,
                           const float* __restrict__ W3, u16* __restrict__ Wt3,
                           const int* __restrict__ ei, int E0, int ET,
                           int* __restrict__ deg, const float* __restrict__ as1,
                           const float* __restrict__ ad1, float* __restrict__ wsd) {
  int i = blockIdx.x * blockDim.x + threadIdx.x;
  if (i < 64 * 512) {          // Wt1[n*64+k] = W1[k*512+n]
    int n = i >> 6, k = i & 63;
    Wt1[n * 64 + k] = f2b(W1[k * 512 + n]);
    return;
  }
  i -= 64 * 512;
  if (i < 512 * 512) {         // Wt2[n*512+k] = W2[k*512+n]
    int n = i >> 9, k = i & 511;
    Wt2[n * 512 + k] = f2b(W2[k * 512 + n]);
    return;
  }
  i -= 512 * 512;
  if (i < 512 * 128) {         // Wt3[n*512+k] = W3[k*128+n]
    int n = i >> 9, k = i & 511;
    Wt3[n * 512 + k] = f2b(W3[k * 128 + n]);
    return;
  }
  i -= 512 * 128;
  if (i < ET) {
    int d = (i < E0) ? ei[E0 + i] : (i - E0);
    atomicAdd(&deg[d], 1);
    return;
  }
  i -= ET;
  if (i < 512) {  // wsd[k][0..3]=W1_h@a_src, [4..7]=W1_h@a_dst (layer-1 proj)
    int k = i >> 3, c8 = i & 7, hh = c8 & 3;
    const float* a = (c8 >= 4) ? ad1 : as1;
    float s = 0.f;
    for (int c = 0; c < 128; ++c) s += W1[k * 512 + hh * 128 + c] * a[hh * 128 + c];
    wsd[k * 8 + c8] = s;
  }
}

// ---------------- bf16 MFMA GEMM (layer 2): LDS XOR-swizzle + 2-phase dbuf -------
__global__ __launch_bounds__(256) void gemm_bf16_gat(
    const u16* __restrict__ A, const u16* __restrict__ Bt, u16* __restrict__ Hb,
    const float* __restrict__ a_src, const float* __restrict__ a_dst,
    float* __restrict__ aS, float* __restrict__ aD, int M, int HC, int K, int Hh,
    int gy, int nStrips) {
  int mIdx, nIdx;
  if (nStrips == 4) {
    int l = blockIdx.x;
    int xcd = l & 7, k = l >> 3;
    nIdx = k & 3;
    mIdx = xcd + 8 * (k >> 2);
    if (mIdx >= gy) return;
  } else {
    mIdx = blockIdx.x;
    nIdx = 0;
  }
  __shared__ u16 As[2][128 * 32];
  __shared__ u16 Bs[2][128 * 32];
  __shared__ float sRed[2][2][128];
  const int tid = threadIdx.x;
  const int w = tid >> 6, lane = tid & 63;
  const int wm = w >> 1, wn = w & 1;
  const int q = lane >> 4, l15 = lane & 15;
  const int nBase = nIdx * 128;
  const int mBase = mIdx * 128;
  const int h = nBase >> 7;
  const int srow = lane >> 2;
  const int ssw = ((lane & 3) ^ ((lane >> 3) & 3)) * 8;
  const int rq = (q ^ ((l15 >> 1) & 3)) * 8;

  f32x4 acc[4][4];
#pragma unroll
  for (int i = 0; i < 4; ++i)
#pragma unroll
    for (int j = 0; j < 4; ++j) acc[i][j] = (f32x4){0.f, 0.f, 0.f, 0.f};

  const int nSteps = K >> 5;
#pragma unroll
  for (int r = 0; r < 2; ++r) {
    int lrow0 = w * 32 + r * 16;
    int ga = mBase + lrow0 + srow;
    if (ga >= M) ga = M - 1;
    gld_lds16(A + (size_t)ga * K + ssw, &As[0][lrow0 * 32]);
    int gb = nBase + lrow0 + srow;
    gld_lds16(Bt + (size_t)gb * K + ssw, &Bs[0][lrow0 * 32]);
  }
  __syncthreads();
  int cur = 0;
  for (int step = 0; step < nSteps; ++step) {
    const int k0n = (step + 1) << 5;
    if (k0n < K) {
#pragma unroll
      for (int r = 0; r < 2; ++r) {
        int lrow0 = w * 32 + r * 16;
        int ga = mBase + lrow0 + srow;
        if (ga >= M) ga = M - 1;
        gld_lds16(A + (size_t)ga * K + k0n + ssw, &As[cur ^ 1][lrow0 * 32]);
        int gb = nBase + lrow0 + srow;
        gld_lds16(Bt + (size_t)gb * K + k0n + ssw, &Bs[cur ^ 1][lrow0 * 32]);
      }
    }
    short8 af[4], bf[4];
#pragma unroll
    for (int i = 0; i < 4; ++i)
      af[i] = *(const short8*)&As[cur][(wm * 64 + i * 16 + l15) * 32 + rq];
#pragma unroll
    for (int j = 0; j < 4; ++j)
      bf[j] = *(const short8*)&Bs[cur][(wn * 64 + j * 16 + l15) * 32 + rq];
#pragma unroll
    for (int i = 0; i < 4; ++i)
#pragma unroll
      for (int j = 0; j < 4; ++j)
        acc[i][j] = __builtin_amdgcn_mfma_f32_16x16x32_bf16(af[i], bf[j], acc[i][j], 0, 0, 0);
    __syncthreads();
    cur ^= 1;
  }

  float asv[4], adv[4];
#pragma unroll
  for (int j = 0; j < 4; ++j) {
    int cw = wn * 64 + j * 16 + l15;
    asv[j] = a_src[h * 128 + cw];
    adv[j] = a_dst[h * 128 + cw];
  }
#pragma unroll
  for (int mi = 0; mi < 4; ++mi) {
#pragma unroll
    for (int r = 0; r < 4; ++r) {
      int row = mBase + wm * 64 + mi * 16 + q * 4 + r;
      float s = 0.f, d = 0.f;
#pragma unroll
      for (int j = 0; j < 4; ++j) {
        float v = acc[mi][j][r];
        s = fmaf(v, asv[j], s);
        d = fmaf(v, adv[j], d);
        if (row < M) Hb[(size_t)row * HC + nBase + wn * 64 + j * 16 + l15] = f2b(v);
      }
#pragma unroll
      for (int o = 8; o; o >>= 1) {
        s += __shfl_xor(s, o);
        d += __shfl_xor(d, o);
      }
      if (l15 == 0) {
        int lr = wm * 64 + mi * 16 + q * 4 + r;
        sRed[0][wn][lr] = s;
        sRed[1][wn][lr] = d;
      }
    }
  }
  __syncthreads();
  if (tid < 128) {
    int row = mBase + tid;
    if (row < M) {
      aS[(size_t)row * Hh + h] = sRed[0][0][tid] + sRed[0][1][tid];
      aD[(size_t)row * Hh + h] = sRed[1][0][tid] + sRed[1][1][tid];
    }
  }
}

// ---------------- layer-3 GEMM: 64-row tiles (782 blocks), fused aS/aD epilogue --
__global__ __launch_bounds__(256) void gemm_bf16_l3(
    const u16* __restrict__ A, const u16* __restrict__ Bt,
    const float* __restrict__ a_src, const float* __restrict__ a_dst,
    u16* __restrict__ Hb, float* __restrict__ aS, float* __restrict__ aD, int M) {
  __shared__ u16 As[2][64 * 32];
  __shared__ u16 Bs[2][128 * 32];
  const int tid = threadIdx.x;
  const int w = tid >> 6, lane = tid & 63;
  const int q = lane >> 4, l15 = lane & 15;
  const int mBase = blockIdx.x * 64;
  const int ssw = ((lane & 3) ^ ((lane >> 3) & 3)) * 8;
  const int rq = (q ^ ((l15 >> 1) & 3)) * 8;
  const int arow = w * 16 + (lane >> 2);

  f32x4 acc[8];
#pragma unroll
  for (int j = 0; j < 8; ++j) acc[j] = (f32x4){0.f, 0.f, 0.f, 0.f};

  {
    int ga = mBase + arow;
    if (ga >= M) ga = M - 1;
    gld_lds16(A + (size_t)ga * 512 + ssw, &As[0][w * 512]);
#pragma unroll
    for (int r = 0; r < 2; ++r) {
      int brow = r * 64 + w * 16 + (lane >> 2);
      gld_lds16(Bt + (size_t)brow * 512 + ssw, &Bs[0][(r * 64 + w * 16) * 32]);
    }
  }
  __syncthreads();
  int cur = 0;
  for (int step = 0; step < 16; ++step) {
    if (step < 15) {
      const int k0n = (step + 1) << 5;
      int ga = mBase + arow;
      if (ga >= M) ga = M - 1;
      gld_lds16(A + (size_t)ga * 512 + k0n + ssw, &As[cur ^ 1][w * 512]);
#pragma unroll
      for (int r = 0; r < 2; ++r) {
        int brow = r * 64 + w * 16 + (lane >> 2);
        gld_lds16(Bt + (size_t)brow * 512 + k0n + ssw,
                  &Bs[cur ^ 1][(r * 64 + w * 16) * 32]);
      }
    }
    short8 af = *(const short8*)&As[cur][(w * 16 + l15) * 32 + rq];
    short8 bf[8];
#pragma unroll
    for (int j = 0; j < 8; ++j)
      bf[j] = *(const short8*)&Bs[cur][(j * 16 + l15) * 32 + rq];
#pragma unroll
    for (int j = 0; j < 8; ++j)
      acc[j] = __builtin_amdgcn_mfma_f32_16x16x32_bf16(af, bf[j], acc[j], 0, 0, 0);
    __syncthreads();
    cur ^= 1;
  }

  float asv[8], adv[8];
#pragma unroll
  for (int j = 0; j < 8; ++j) {
    asv[j] = a_src[j * 16 + l15];
    adv[j] = a_dst[j * 16 + l15];
  }
#pragma unroll
  for (int r = 0; r < 4; ++r) {
    int row = mBase + w * 16 + q * 4 + r;
    float s = 0.f, d = 0.f;
#pragma unroll
    for (int j = 0; j < 8; ++j) {
      float v = acc[j][r];
      s = fmaf(v, asv[j], s);
      d = fmaf(v, adv[j], d);
      if (row < M) Hb[(size_t)row * 128 + j * 16 + l15] = f2b(v);
    }
#pragma unroll
    for (int o = 8; o; o >>= 1) {
      s += __shfl_xor(s, o);
      d += __shfl_xor(d, o);
    }
    if (l15 == 0 && row < M) {
      aS[row] = s;
      aD[row] = d;
    }
  }
}

// ---------------- layer-1 block-diagonal GEMM (swizzle + dbuf, K=64) ------------
__global__ __launch_bounds__(256) void gemm_bd_l1(
    const u16* __restrict__ A, const u16* __restrict__ Bt,
    const float* __restrict__ bias, u16* __restrict__ outB, int M, int gy) {
  int l = blockIdx.x;
  int xcd = l & 7, kk = l >> 3;
  int nIdx = kk & 3;
  int mIdx = xcd + 8 * (kk >> 2);
  if (mIdx >= gy) return;
  __shared__ u16 As[2][128 * 32];
  __shared__ u16 Bs[2][128 * 32];
  const int tid = threadIdx.x;
  const int w = tid >> 6, lane = tid & 63;
  const int wm = w >> 1, wn = w & 1;
  const int q = lane >> 4, l15 = lane & 15;
  const int nBase = nIdx * 128, mBase = mIdx * 128;
  const int srow = lane >> 2;
  const int ssw = ((lane & 3) ^ ((lane >> 3) & 3)) * 8;
  const int rq = (q ^ ((l15 >> 1) & 3)) * 8;

  f32x4 acc[4][4];
#pragma unroll
  for (int i = 0; i < 4; ++i)
#pragma unroll
    for (int j = 0; j < 4; ++j) acc[i][j] = (f32x4){0.f, 0.f, 0.f, 0.f};

#pragma unroll
  for (int r = 0; r < 2; ++r) {
    int lrow0 = w * 32 + r * 16;
    int ga = mBase + lrow0 + srow;
    if (ga >= M) ga = M - 1;
    gld_lds16(A + (size_t)ga * 256 + nIdx * 64 + ssw, &As[0][lrow0 * 32]);
    int gb = nBase + lrow0 + srow;
    gld_lds16(Bt + (size_t)gb * 64 + ssw, &Bs[0][lrow0 * 32]);
  }
  __syncthreads();
  int cur = 0;
#pragma unroll
  for (int step = 0; step < 2; ++step) {
    if (step == 0) {
#pragma unroll
      for (int r = 0; r < 2; ++r) {
        int lrow0 = w * 32 + r * 16;
        int ga = mBase + lrow0 + srow;
        if (ga >= M) ga = M - 1;
        gld_lds16(A + (size_t)ga * 256 + nIdx * 64 + 32 + ssw, &As[1][lrow0 * 32]);
        int gb = nBase + lrow0 + srow;
        gld_lds16(Bt + (size_t)gb * 64 + 32 + ssw, &Bs[1][lrow0 * 32]);
      }
    }
    short8 af[4], bf[4];
#pragma unroll
    for (int i = 0; i < 4; ++i)
      af[i] = *(const short8*)&As[cur][(wm * 64 + i * 16 + l15) * 32 + rq];
#pragma unroll
    for (int j = 0; j < 4; ++j)
      bf[j] = *(const short8*)&Bs[cur][(wn * 64 + j * 16 + l15) * 32 + rq];
#pragma unroll
    for (int i = 0; i < 4; ++i)
#pragma unroll
      for (int j = 0; j < 4; ++j)
        acc[i][j] = __builtin_amdgcn_mfma_f32_16x16x32_bf16(af[i], bf[j], acc[i][j], 0, 0, 0);
    __syncthreads();
    cur ^= 1;
  }

  float bvv[4];
#pragma unroll
  for (int j = 0; j < 4; ++j) bvv[j] = bias[nBase + wn * 64 + j * 16 + l15];
#pragma unroll
  for (int mi = 0; mi < 4; ++mi)
#pragma unroll
    for (int r = 0; r < 4; ++r) {
      int row = mBase + wm * 64 + mi * 16 + q * 4 + r;
      if (row < M) {
#pragma unroll
        for (int j = 0; j < 4; ++j) {
          float v = elu1(acc[mi][j][r] + bvv[j]);
          outB[(size_t)row * 512 + nBase + wn * 64 + j * 16 + l15] = f2b(v);
        }
      }
    }
}

// ---------------- CSR scan ----------------
__global__ __launch_bounds__(256) void scan_chunk(const int* __restrict__ deg,
                                                  int* __restrict__ incl,
                                                  int* __restrict__ bsums, int N) {
  __shared__ int sdata[256];
  const int t = threadIdx.x;
  const int base = blockIdx.x * 2048;
  int v[8];
  int sum = 0;
#pragma unroll
  for (int i = 0; i < 8; ++i) {
    int idx = base + t * 8 + i;
    v[i] = (idx < N) ? deg[idx] : 0;
    sum += v[i];
  }
  sdata[t] = sum;
  __syncthreads();
  for (int off = 1; off < 256; off <<= 1) {
    int x = (t >= off) ? sdata[t - off] : 0;
    __syncthreads();
    sdata[t] += x;
    __syncthreads();
  }
  int run = (t > 0) ? sdata[t - 1] : 0;
#pragma unroll
  for (int i = 0; i < 8; ++i) {
    int idx = base + t * 8 + i;
    run += v[i];
    if (idx < N) incl[idx] = run;
  }
  if (t == 255) bsums[blockIdx.x] = sdata[255];
}

__global__ void scan_final(const int* __restrict__ incl, const int* __restrict__ bsums,
                           int* __restrict__ rowptr, int N, int nb) {
  int i = blockIdx.x * blockDim.x + threadIdx.x;
  if (i >= N) return;
  int chunk = i >> 11;
  int pre = 0;
  for (int j = 0; j < chunk; ++j) pre += bsums[j];
  rowptr[i + 1] = incl[i] + pre;
  if (i == 0) rowptr[0] = 0;
}

// csr_fill: writes layer-1 elog inline (asad_x runs before this).
__global__ void csr_fill(const int* __restrict__ ei, int E0, int ET,
                         const int* __restrict__ rowptr, int* __restrict__ cnt,
                         int* __restrict__ csr_src, int* __restrict__ csr_dst,
                         const float* __restrict__ aS, const float* __restrict__ aD,
                         float* __restrict__ elog) {
  int e = blockIdx.x * blockDim.x + threadIdx.x;
  if (e >= ET) return;
  int s, d;
  if (e < E0) { s = ei[e]; d = ei[E0 + e]; }
  else        { s = e - E0; d = e - E0; }
  int pos = atomicAdd(&cnt[d], 1);
  int slot = rowptr[d] + pos;
  csr_src[slot] = s;
  csr_dst[slot] = d;
  float4 a = *(const float4*)&aS[(size_t)s * 4];
  float4 b = *(const float4*)&aD[(size_t)d * 4];
  float4 r;
  r.x = lrelu(a.x + b.x);
  r.y = lrelu(a.y + b.y);
  r.z = lrelu(a.z + b.z);
  r.w = lrelu(a.w + b.w);
  *(float4*)&elog[(size_t)slot * 4] = r;
}

// aS[v,h] = x[v]·ws_h, aD[v,h] = x[v]·wd_h — one wave per node, f32 path.
__global__ __launch_bounds__(256) void asad_x(const float* __restrict__ xf,
                                              const float* __restrict__ wsd,
                                              float* __restrict__ aS,
                                              float* __restrict__ aD, int N) {
  const int wid = (int)((blockIdx.x * (blockDim.x >> 6)) + (threadIdx.x >> 6));
  const int lane = threadIdx.x & 63;
  if (wid >= N) return;
  float xv = xf[(size_t)wid * 64 + lane];
  float4 w0 = *(const float4*)&wsd[lane * 8];
  float4 w1 = *(const float4*)&wsd[lane * 8 + 4];
  float s[8] = {xv * w0.x, xv * w0.y, xv * w0.z, xv * w0.w,
                xv * w1.x, xv * w1.y, xv * w1.z, xv * w1.w};
#pragma unroll
  for (int i = 0; i < 8; ++i)
#pragma unroll
    for (int o = 32; o; o >>= 1) s[i] += __shfl_xor(s[i], o);
  if (lane == 0) {
    *(float4*)&aS[(size_t)wid * 4] = make_float4(s[0], s[1], s[2], s[3]);
    *(float4*)&aD[(size_t)wid * 4] = make_float4(s[4], s[5], s[6], s[7]);
  }
}

// ---------------- edge-parallel logit precompute (layers 2,3) ----------------
__global__ __launch_bounds__(256) void edge_logits(const int* __restrict__ csr_src,
                                                   const int* __restrict__ csr_dst,
                                                   const float* __restrict__ aS,
                                                   const float* __restrict__ aD,
                                                   float* __restrict__ elog, int ET,
                                                   int Hh) {
  int e = blockIdx.x * blockDim.x + threadIdx.x;
  if (e >= ET) return;
  int s = csr_src[e], d = csr_dst[e];
  if (Hh == 4) {
    float4 a = *(const float4*)&aS[(size_t)s * 4];
    float4 b = *(const float4*)&aD[(size_t)d * 4];
    float4 r;
    r.x = lrelu(a.x + b.x);
    r.y = lrelu(a.y + b.y);
    r.z = lrelu(a.z + b.z);
    r.w = lrelu(a.w + b.w);
    *(float4*)&elog[(size_t)e * 4] = r;
  } else {
    elog[e] = lrelu(aS[s] + aD[d]);
  }
}

// ---------------- layer-1 input-side aggregation ----------------
__global__ __launch_bounds__(256) void gat_agg_x(
    const int* __restrict__ rowptr, const int* __restrict__ csr_src,
    const float* __restrict__ xf, const float* __restrict__ elog,
    u16* __restrict__ aggB, int N) {
  const int wid = (int)((blockIdx.x * (blockDim.x >> 6)) + (threadIdx.x >> 6));
  const int lane = threadIdx.x & 63;
  if (wid >= N) return;
  const int beg = rowptr[wid];
  const int deg = rowptr[wid + 1] - beg;
  const int h = lane >> 4;
  const int e16 = lane & 15;
  float acc[4] = {};

  if (deg <= 16) {
    int srcv = 0;
    float l = -1e30f;
    if (e16 < deg) {
      srcv = csr_src[beg + e16];
      l = elog[(size_t)(beg + e16) * 4 + h];
    }
    float xv[16];
#pragma unroll
    for (int j = 0; j < 16; ++j)
      if (j < deg) {
        int s = __shfl(srcv, j);
        xv[j] = xf[(size_t)s * 64 + lane];
      }
    float m = l;
#pragma unroll
    for (int o = 8; o; o >>= 1) m = fmaxf(m, __shfl_xor(m, o));
    float pexp = (e16 < deg) ? __expf(l - m) : 0.f;
    float cs = pexp;
#pragma unroll
    for (int o = 8; o; o >>= 1) cs += __shfl_xor(cs, o);
    pexp *= (1.f / cs);
#pragma unroll
    for (int j = 0; j < 16; ++j)
      if (j < deg) {
        float w0 = __shfl(pexp, j);
        float w1 = __shfl(pexp, 16 | j);
        float w2 = __shfl(pexp, 32 | j);
        float w3 = __shfl(pexp, 48 | j);
        acc[0] = fmaf(w0, xv[j], acc[0]);
        acc[1] = fmaf(w1, xv[j], acc[1]);
        acc[2] = fmaf(w2, xv[j], acc[2]);
        acc[3] = fmaf(w3, xv[j], acc[3]);
      }
  } else {
    float m = -1e30f, ssum = 0.f;
    for (int c = 0; c < deg; c += 16) {
      const int ce = min(16, deg - c);
      int srcv = 0;
      float l = -1e30f;
      if (e16 < ce) {
        srcv = csr_src[beg + c + e16];
        l = elog[(size_t)(beg + c + e16) * 4 + h];
      }
      float xv[16];
#pragma unroll
      for (int j = 0; j < 16; ++j)
        if (j < ce) {
          int s = __shfl(srcv, j);
          xv[j] = xf[(size_t)s * 64 + lane];
        }
      float cm = l;
#pragma unroll
      for (int o = 8; o; o >>= 1) cm = fmaxf(cm, __shfl_xor(cm, o));
      float pexp, cs;
      if (c == 0) {
        m = cm;
        pexp = (e16 < ce) ? __expf(l - m) : 0.f;
        cs = pexp;
#pragma unroll
        for (int o = 8; o; o >>= 1) cs += __shfl_xor(cs, o);
        ssum = cs;
      } else {
        float newm = fmaxf(m, cm);
        float r = __expf(m - newm);
        m = newm;
        pexp = (e16 < ce) ? __expf(l - m) : 0.f;
        cs = pexp;
#pragma unroll
        for (int o = 8; o; o >>= 1) cs += __shfl_xor(cs, o);
        ssum = ssum * r + cs;
#pragma unroll
        for (int i = 0; i < 4; ++i) acc[i] *= r;
      }
#pragma unroll
      for (int j = 0; j < 16; ++j)
        if (j < ce) {
          float w0 = __shfl(pexp, j);
          float w1 = __shfl(pexp, 16 | j);
          float w2 = __shfl(pexp, 32 | j);
          float w3 = __shfl(pexp, 48 | j);
          acc[0] = fmaf(w0, xv[j], acc[0]);
          acc[1] = fmaf(w1, xv[j], acc[1]);
          acc[2] = fmaf(w2, xv[j], acc[2]);
          acc[3] = fmaf(w3, xv[j], acc[3]);
        }
    }
    const float inv = 1.f / ssum;
#pragma unroll
    for (int i = 0; i < 4; ++i) acc[i] *= inv;
  }
#pragma unroll
  for (int hh = 0; hh < 4; ++hh)
    aggB[((size_t)wid * 4 + hh) * 64 + lane] = f2b(acc[hh]);
}

// bf16 pair unpack: lo = u<<16, hi = u & 0xffff0000 — 1 VALU op per element.
#define ACC8(A, pv, wgt)                                             \
  A[0] = fmaf(wgt, __uint_as_float(pv.x << 16), A[0]);               \
  A[1] = fmaf(wgt, __uint_as_float(pv.x & 0xffff0000u), A[1]);       \
  A[2] = fmaf(wgt, __uint_as_float(pv.y << 16), A[2]);               \
  A[3] = fmaf(wgt, __uint_as_float(pv.y & 0xffff0000u), A[3]);       \
  A[4] = fmaf(wgt, __uint_as_float(pv.z << 16), A[4]);               \
  A[5] = fmaf(wgt, __uint_as_float(pv.z & 0xffff0000u), A[5]);       \
  A[6] = fmaf(wgt, __uint_as_float(pv.w << 16), A[6]);               \
  A[7] = fmaf(wgt, __uint_as_float(pv.w & 0xffff0000u), A[7]);

// ---------------- fused softmax + aggregate, Hh=4 (layer 2): r6 structure -------
// At its algorithmic gather floor (~460MB demand @ ~6.5TB/s delivered).
__global__ __launch_bounds__(256) void gat_fused_agg(
    const int* __restrict__ rowptr, const int* __restrict__ csr_src,
    const u16* __restrict__ Hb, const float* __restrict__ elog,
    const float* __restrict__ bias, u16* __restrict__ outB, int N) {
  const int wid = (int)((blockIdx.x * (blockDim.x >> 6)) + (threadIdx.x >> 6));
  const int lane = threadIdx.x & 63;
  if (wid >= N) return;
  const int beg = rowptr[wid];
  const int deg = rowptr[wid + 1] - beg;

  const int h = lane >> 4;
  const int e16 = lane & 15;
  const int c0 = lane * 8;
  const int hbase = lane & 48;
  float acc[8] = {};

  if (deg <= 16) {
    int srcv = 0;
    float l = -1e30f;
    if (e16 < deg) {
      srcv = csr_src[beg + e16];
      l = elog[(size_t)(beg + e16) * 4 + h];
    }
    uint4 pC[4];
#pragma unroll
    for (int j = 0; j < 4; ++j)
      if (j < deg) {
        int s = __shfl(srcv, j);
        pC[j] = *(const uint4*)&Hb[(size_t)s * 512 + c0];
      }
    float m = l;
#pragma unroll
    for (int o = 8; o; o >>= 1) m = fmaxf(m, __shfl_xor(m, o));
    float pexp = (e16 < deg) ? __expf(l - m) : 0.f;
    float cs = pexp;
#pragma unroll
    for (int o = 8; o; o >>= 1) cs += __shfl_xor(cs, o);
    pexp *= (1.f / cs);
    int e = 0;
    for (; e + 4 < deg; e += 4) {
      uint4 pN[4];
      int rem = deg - e - 4;
#pragma unroll
      for (int j = 0; j < 4; ++j)
        if (j < rem) {
          int s = __shfl(srcv, e + 4 + j);
          pN[j] = *(const uint4*)&Hb[(size_t)s * 512 + c0];
        }
#pragma unroll
      for (int j = 0; j < 4; ++j) {
        float wgt = __shfl(pexp, hbase | (e + j));
        ACC8(acc, pC[j], wgt)
      }
#pragma unroll
      for (int j = 0; j < 4; ++j) pC[j] = pN[j];
    }
#pragma unroll
    for (int j = 0; j < 4; ++j)
      if (j < deg - e) {
        float wgt = __shfl(pexp, hbase | (e + j));
        ACC8(acc, pC[j], wgt)
      }
  } else {
    float m = -1e30f, ssum = 0.f;
    for (int c = 0; c < deg; c += 16) {
      const int ce = min(16, deg - c);
      int srcv = 0;
      float l = -1e30f;
      if (e16 < ce) {
        srcv = csr_src[beg + c + e16];
        l = elog[(size_t)(beg + c + e16) * 4 + h];
      }
      float cm = l;
#pragma unroll
      for (int o = 8; o; o >>= 1) cm = fmaxf(cm, __shfl_xor(cm, o));
      float pexp, cs;
      if (c == 0) {
        m = cm;
        pexp = __expf(l - m);
        cs = pexp;
#pragma unroll
        for (int o = 8; o; o >>= 1) cs += __shfl_xor(cs, o);
        ssum = cs;
      } else {
        float newm = fmaxf(m, cm);
        float r = __expf(m - newm);
        m = newm;
        pexp = __expf(l - m);
        cs = pexp;
#pragma unroll
        for (int o = 8; o; o >>= 1) cs += __shfl_xor(cs, o);
        ssum = ssum * r + cs;
#pragma unroll
        for (int i = 0; i < 8; ++i) acc[i] *= r;
      }
      int e = 0;
      for (; e + 4 <= ce; e += 4) {
        int se0 = __shfl(srcv, e + 0), se1 = __shfl(srcv, e + 1);
        int se2 = __shfl(srcv, e + 2), se3 = __shfl(srcv, e + 3);
        float w0 = __shfl(pexp, hbase | (e + 0)), w1 = __shfl(pexp, hbase | (e + 1));
        float w2 = __shfl(pexp, hbase | (e + 2)), w3 = __shfl(pexp, hbase | (e + 3));
        uint4 p0 = *(const uint4*)&Hb[(size_t)se0 * 512 + c0];
        uint4 p1 = *(const uint4*)&Hb[(size_t)se1 * 512 + c0];
        uint4 p2 = *(const uint4*)&Hb[(size_t)se2 * 512 + c0];
        uint4 p3 = *(const uint4*)&Hb[(size_t)se3 * 512 + c0];
        ACC8(acc, p0, w0)
        ACC8(acc, p1, w1)
        ACC8(acc, p2, w2)
        ACC8(acc, p3, w3)
      }
      for (; e < ce; ++e) {
        int se = __shfl(srcv, e);
        float wgt = __shfl(pexp, hbase | e);
        uint4 pv = *(const uint4*)&Hb[(size_t)se * 512 + c0];
        ACC8(acc, pv, wgt)
      }
    }
    const float inv = 1.f / ssum;
#pragma unroll
    for (int i = 0; i < 8; ++i) acc[i] *= inv;
  }

  float bv[8];
  *(float4*)&bv[0] = *(const float4*)&bias[c0];
  *(float4*)&bv[4] = *(const float4*)&bias[c0 + 4];
  u16 packed[8];
#pragma unroll
  for (int i = 0; i < 8; ++i) {
    float v = elu1(acc[i] + bv[i]);
    packed[i] = f2b(v);
  }
  *(uint4*)&outB[(size_t)wid * 512 + c0] = *(const uint4*)packed;
}

// ---------------- Hh=1 aggregate (layer 3) ----------------
__global__ __launch_bounds__(256) void gat_agg_h1(
    const int* __restrict__ rowptr, const int* __restrict__ csr_src,
    const u16* __restrict__ Hb, const float* __restrict__ elog,
    const float* __restrict__ bias, float* __restrict__ outF, int N) {
  const int wid = (int)((blockIdx.x * (blockDim.x >> 6)) + (threadIdx.x >> 6));
  const int lane = threadIdx.x & 63;
  if (wid >= N) return;
  const int beg = rowptr[wid];
  const int deg = rowptr[wid + 1] - beg;
  const int g = lane & 15;
  const int es = lane >> 4;
  const int c0 = g * 8;
  float acc[8] = {};

  if (deg <= 64) {
    int srcv = 0;
    float l = -1e30f;
    if (lane < deg) {
      srcv = csr_src[beg + lane];
      l = elog[beg + lane];
    }
    const int dm1 = deg - 1;
    uint4 pC;
    {
      int s = __shfl(srcv, min(es, dm1));
      pC = *(const uint4*)&Hb[(size_t)s * 128 + c0];
    }
    float m = l;
#pragma unroll
    for (int o = 32; o; o >>= 1) m = fmaxf(m, __shfl_xor(m, o));
    float pexp = (lane < deg) ? __expf(l - m) : 0.f;
    float cs = pexp;
#pragma unroll
    for (int o = 32; o; o >>= 1) cs += __shfl_xor(cs, o);
    pexp *= (1.f / cs);
    int t = 0;
    for (; t + 4 < deg; t += 4) {
      uint4 pN;
      {
        int s = __shfl(srcv, min(t + 4 + es, dm1));
        pN = *(const uint4*)&Hb[(size_t)s * 128 + c0];
      }
      float w = __shfl(pexp, t + es);
      ACC8(acc, pC, w)
      pC = pN;
    }
    {
      int idx = t + es;
      float w = __shfl(pexp, min(idx, dm1));
      if (idx > dm1) w = 0.f;
      ACC8(acc, pC, w)
    }
  } else {
    float m = -1e30f, ssum = 0.f;
    for (int c = 0; c < deg; c += 64) {
      const int ce = min(64, deg - c);
      int srcv = 0;
      float l = -1e30f;
      if (lane < ce) {
        srcv = csr_src[beg + c + lane];
        l = elog[beg + c + lane];
      }
      float cm = l;
#pragma unroll
      for (int o = 32; o; o >>= 1) cm = fmaxf(cm, __shfl_xor(cm, o));
      float pexp, cs;
      if (c == 0) {
        m = cm;
        pexp = __expf(l - m);
        cs = pexp;
#pragma unroll
        for (int o = 32; o; o >>= 1) cs += __shfl_xor(cs, o);
        ssum = cs;
      } else {
        float newm = fmaxf(m, cm);
        float r = __expf(m - newm);
        m = newm;
        pexp = __expf(l - m);
        cs = pexp;
#pragma unroll
        for (int o = 32; o; o >>= 1) cs += __shfl_xor(cs, o);
        ssum = ssum * r + cs;
#pragma unroll
        for (int i = 0; i < 8; ++i) acc[i] *= r;
      }
      for (int t = 0; t < ce; t += 4) {
        int idx = t + es;
        int se = __shfl(srcv, idx & 63);
        float wgt = __shfl(pexp, idx & 63);
        if (idx < ce) {
          uint4 pv = *(const uint4*)&Hb[(size_t)se * 128 + c0];
          ACC8(acc, pv, wgt)
        }
      }
    }
    const float inv = 1.f / ssum;
#pragma unroll
    for (int i = 0; i < 8; ++i) acc[i] *= inv;
  }
#pragma unroll
  for (int i = 0; i < 8; ++i) {
    acc[i] += __shfl_xor(acc[i], 16);
    acc[i] += __shfl_xor(acc[i], 32);
  }
  if (lane < 16) {
    float o[8];
#pragma unroll
    for (int i = 0; i < 8; ++i) o[i] = elu1(acc[i] + bias[c0 + i]);
    *(float4*)&outF[(size_t)wid * 128 + c0] = make_float4(o[0], o[1], o[2], o[3]);
    *(float4*)&outF[(size_t)wid * 128 + c0 + 4] = make_float4(o[4], o[5], o[6], o[7]);
  }
}

// ---------------- fused FC head ----------------
__global__ __launch_bounds__(256) void fc_head(const float* __restrict__ A,
                                               const float* __restrict__ B,
                                               const float* __restrict__ bias,
                                               const float* __restrict__ w2,
                                               const float* __restrict__ b2,
                                               float* __restrict__ out, int M) {
  __shared__ float As[16][64];
  __shared__ float Bs[16][64];
  __shared__ float sP[64][17];
  const int tid = threadIdx.x;
  const int tx = tid & 15, ty = tid >> 4;
  const int mBase = blockIdx.y * 64;
  const int aRow = tid >> 2;
  const int aK = (tid & 3) << 2;
  const int bC = tid & 63;
  const int bR0 = tid >> 6;
  const int K = 128, N = 64;
  float acc[4][4] = {};
  for (int k0 = 0; k0 < K; k0 += 16) {
    float4 av = make_float4(0.f, 0.f, 0.f, 0.f);
    int gr = mBase + aRow;
    if (gr < M) av = *(const float4*)&A[(size_t)gr * K + k0 + aK];
    As[aK + 0][aRow] = av.x;
    As[aK + 1][aRow] = av.y;
    As[aK + 2][aRow] = av.z;
    As[aK + 3][aRow] = av.w;
#pragma unroll
    for (int i = 0; i < 4; ++i) {
      int r = bR0 + i * 4;
      Bs[r][bC] = B[(size_t)(k0 + r) * N + bC];
    }
    __syncthreads();
#pragma unroll
    for (int k = 0; k < 16; ++k) {
      float4 a = *(const float4*)&As[k][ty * 4];
      float4 b = *(const float4*)&Bs[k][tx * 4];
      float ar[4] = {a.x, a.y, a.z, a.w};
      float br[4] = {b.x, b.y, b.z, b.w};
#pragma unroll
      for (int i = 0; i < 4; ++i)
#pragma unroll
        for (int j = 0; j < 4; ++j) acc[i][j] = fmaf(ar[i], br[j], acc[i][j]);
    }
    __syncthreads();
  }
  float4 bv = *(const float4*)&bias[tx * 4];
  float4 wv = *(const float4*)&w2[tx * 4];
#pragma unroll
  for (int i = 0; i < 4; ++i) {
    float p = 0.f;
    p = fmaf(fmaxf(acc[i][0] + bv.x, 0.f), wv.x, p);
    p = fmaf(fmaxf(acc[i][1] + bv.y, 0.f), wv.y, p);
    p = fmaf(fmaxf(acc[i][2] + bv.z, 0.f), wv.z, p);
    p = fmaf(fmaxf(acc[i][3] + bv.w, 0.f), wv.w, p);
    sP[ty * 4 + i][tx] = p;
  }
  __syncthreads();
  if (tid < 64) {
    int row = mBase + tid;
    if (row < M) {
      float s = 0.f;
#pragma unroll
      for (int t = 0; t < 16; ++t) s += sP[tid][t];
      out[row] = 1.f / (1.f + expf(-(s + b2[0])));
    }
  }
}

// ---------------- launch ----------------
extern "C" void kernel_launch(void* const* d_in, const int* in_sizes, int n_in,
                              void* d_out, int out_size, void* d_ws, size_t ws_size,
                              hipStream_t stream) {
  const float* x    = (const float*)d_in[0];
  const int*   ei   = (const int*)d_in[1];
  const float* W1   = (const float*)d_in[2];
  const float* as1  = (const float*)d_in[3];
  const float* ad1  = (const float*)d_in[4];
  const float* b1   = (const float*)d_in[5];
  const float* W2   = (const float*)d_in[6];
  const float* as2  = (const float*)d_in[7];
  const float* ad2  = (const float*)d_in[8];
  const float* b2   = (const float*)d_in[9];
  const float* W3   = (const float*)d_in[10];
  const float* as3  = (const float*)d_in[11];
  const float* ad3  = (const float*)d_in[12];
  const float* b3   = (const float*)d_in[13];
  const float* fc1w = (const float*)d_in[14];
  const float* fc1b = (const float*)d_in[15];
  const float* fc2w = (const float*)d_in[16];
  const float* fc2b = (const float*)d_in[17];
  float* out = (float*)d_out;

  const int N  = in_sizes[0] / 64;  // 50000
  const int E0 = in_sizes[1] / 2;   // 400000
  const int ET = E0 + N;

  char* ws = (char*)d_ws;
  size_t off = 0;
  auto alloc = [&](size_t bytes) -> void* {
    void* p = ws + off;
    off += (bytes + 255) & ~(size_t)255;
    return p;
  };
  u16*   bufXb   = (u16*)alloc((size_t)N * 512 * 2);
  u16*   bufHb   = (u16*)alloc((size_t)N * 512 * 2);
  float* bufF    = (float*)alloc((size_t)N * 128 * 4);
  float* aS      = (float*)alloc((size_t)N * 4 * 4);
  float* aD      = (float*)alloc((size_t)N * 4 * 4);
  u16*   Wt1     = (u16*)alloc((size_t)512 * 64 * 2);
  u16*   Wt2     = (u16*)alloc((size_t)512 * 512 * 2);
  u16*   Wt3     = (u16*)alloc((size_t)128 * 512 * 2);
  u16*   aggB    = (u16*)alloc((size_t)N * 256 * 2);
  float* wsd     = (float*)alloc((size_t)64 * 8 * 4);
  int*   degcnt  = (int*)alloc((size_t)2 * N * 4);
  int*   deg     = degcnt;
  int*   cnt     = degcnt + N;
  int*   incl    = (int*)alloc((size_t)N * 4);
  int*   rowptr  = (int*)alloc((size_t)(N + 1) * 4);
  int*   bsums   = (int*)alloc(256 * 4);
  int*   csr_src = (int*)alloc((size_t)ET * 4);
  int*   csr_dst = (int*)alloc((size_t)ET * 4);
  float* elog    = (float*)alloc((size_t)ET * 4 * 4);  // [e][h], Hh<=4
  (void)ws_size; (void)n_in; (void)out_size;

  // ---- prep: zero deg/cnt, weight casts + degree count + wsd ----
  hipMemsetAsync(degcnt, 0, (size_t)2 * N * 4, stream);
  const int prepTotal = 64 * 512 + 512 * 512 + 512 * 128 + ET + 512;
  hipLaunchKernelGGL(fused_prep, dim3((prepTotal + 255) / 256), dim3(256), 0, stream,
                     W1, Wt1, W2, Wt2, W3, Wt3, ei, E0, ET, deg, as1, ad1, wsd);

  // ---- CSR scan ----
  int nb = (N + 2047) / 2048;
  hipLaunchKernelGGL(scan_chunk, dim3(nb), dim3(256), 0, stream, deg, incl, bsums, N);
  hipLaunchKernelGGL(scan_final, dim3((N + 255) / 256), dim3(256), 0, stream, incl, bsums,
                     rowptr, N, nb);

  const int gy = (N + 127) / 128;                 // 391 m-tiles
  const int grid4 = ((gy + 7) / 8) * 8 * 4;       // XCD-swizzled 1-D grid, 4 strips
  const int aggGrid = (N + 3) / 4;                // 4 waves x 1 node per block
  int eb = (ET + 255) / 256;

  // ---- layer 1: aS/aD first (x-based), then csr_fill writes elog1 inline ----
  hipLaunchKernelGGL(asad_x, dim3(aggGrid), dim3(256), 0, stream, x, wsd, aS, aD, N);
  hipLaunchKernelGGL(csr_fill, dim3(eb), dim3(256), 0, stream, ei, E0, ET, rowptr, cnt,
                     csr_src, csr_dst, aS, aD, elog);
  hipLaunchKernelGGL(gat_agg_x, dim3(aggGrid), dim3(256), 0, stream, rowptr, csr_src, x,
                     elog, aggB, N);
  hipLaunchKernelGGL(gemm_bd_l1, dim3(grid4), dim3(256), 0, stream, aggB, Wt1, b1,
                     bufXb, N, gy);

  // ---- layer 2: [N,512] -> [N,512] ----
  hipLaunchKernelGGL(gemm_bf16_gat, dim3(grid4), dim3(256), 0, stream, bufXb, Wt2, bufHb,
                     as2, ad2, aS, aD, N, 512, 512, 4, gy, 4);
  hipLaunchKernelGGL(edge_logits, dim3(eb), dim3(256), 0, stream, csr_src, csr_dst, aS,
                     aD, elog, ET, 4);
  hipLaunchKernelGGL(gat_fused_agg, dim3(aggGrid), dim3(256), 0, stream, rowptr,
                     csr_src, bufHb, elog, b2, bufXb, N);

  // ---- layer 3: [N,512] -> [N,128], heads=1, 64-row tiles ----
  hipLaunchKernelGGL(gemm_bf16_l3, dim3((N + 63) / 64), dim3(256), 0, stream, bufXb,
                     Wt3, as3, ad3, bufHb, aS, aD, N);
  hipLaunchKernelGGL(edge_logits, dim3(eb), dim3(256), 0, stream, csr_src, csr_dst, aS,
                     aD, elog, ET, 1);
  hipLaunchKernelGGL(gat_agg_h1, dim3(aggGrid), dim3(256), 0, stream, rowptr, csr_src,
                     bufHb, elog, b3, bufF, N);

  hipLaunchKernelGGL(fc_head, dim3(1, (N + 63) / 64), dim3(256), 0, stream, bufF, fc1w,
                     fc1b, fc2w, fc2b, out, N);
}